// Round 6
// baseline (371.985 us; speedup 1.0000x reference)
//
#include <hip/hip_runtime.h>

#define OUTN 8192
#define INN  4096
#define BN   128

namespace {

typedef __attribute__((ext_vector_type(8))) short bf16x8;   // 8 bf16 (4 VGPRs)
typedef __attribute__((ext_vector_type(4))) float f32x4;

struct alignas(16) f4 { float v[4]; };
struct alignas(8)  h4 { short v[4]; };

constexpr float C_HLOG2PI = 0.91893853f;   // 0.5*log(2*pi)
constexpr float C_LN2     = 0.69314718f;

__device__ __forceinline__ short f2bf(float f) {
    unsigned u = __float_as_uint(f);
    u += 0x7fffu + ((u >> 16) & 1u);       // round-to-nearest-even
    return (short)(u >> 16);
}

// ---- full-form helpers (tiny bias kernel only) ----
__device__ __forceinline__ float prior_lp(float w) {
    float lp1 = -0.5f * w * w - C_HLOG2PI;
    float a   = w * 400.0f;
    float lp2 = -0.5f * a * a + 5.0725261f;
    return __logf(0.5f * __expf(lp1) + 0.5f * __expf(lp2));
}
__device__ __forceinline__ float post_lp(float w, float pi_, float s1, float ls1,
                                         float s2, float ls2) {
    float u1  = __fdividef(w, s1);
    float u2  = __fdividef(w, s2);
    float lq1 = -0.5f * u1 * u1 - ls1 - C_HLOG2PI;
    float lq2 = -0.5f * u2 * u2 - ls2 - C_HLOG2PI;
    return __logf(pi_ * __expf(lq1) + (1.0f - pi_) * __expf(lq2));
}
__device__ __forceinline__ float sample_w(float pi_, float rho1, float rho2, float ep,
                                          float g0, float g1,
                                          float& s1, float& ls1, float& s2, float& ls2) {
    s1  = __logf(1.0f + __expf(rho1));
    s2  = __logf(1.0f + __expf(rho2));
    ls1 = __logf(s1);
    ls2 = __logf(s2);
    bool mode1 = ((1.0f - pi_) + g1) > (pi_ + g0);
    return (mode1 ? s1 : s2) * ep;
}

constexpr int OT = 32;    // output rows per tile
constexpr int KC = 32;    // K-chunk (== MFMA K)
constexpr int NT = 256;
constexpr int KSTR = 40;  // bf16 LDS row stride (80 B: 16B-aligned, bank-spread)

__global__ __launch_bounds__(256)
void xcast(const float* __restrict__ x, short* __restrict__ xb)
{
    const int i = (blockIdx.x * 256 + threadIdx.x) * 8;   // 256 blocks
    f4 a = *(const f4*)&x[i];
    f4 b = *(const f4*)&x[i + 4];
    h4 o0, o1;
    #pragma unroll
    for (int j = 0; j < 4; ++j) { o0.v[j] = f2bf(a.v[j]); o1.v[j] = f2bf(b.v[j]); }
    *(h4*)&xb[i]     = o0;
    *(h4*)&xb[i + 4] = o1;
}

__global__ __launch_bounds__(NT, 8)
void bayes_main(const short* __restrict__ xb,      // x in bf16, [BN][INN]
                const float* __restrict__ w_pi,
                const float* __restrict__ w_rho1,
                const float* __restrict__ w_rho2,
                const float* __restrict__ eps_w,
                const float* __restrict__ gum_w,
                const float* __restrict__ bias,    // non-null only when nsplit==1
                float* __restrict__ out,
                float* __restrict__ pbuf,
                float* __restrict__ partials,
                int kps)
{
    __shared__ alignas(16) short Wt[OT][KSTR];   // W tile [o][k] bf16
    __shared__ alignas(16) short Xs[BN][KSTR];   // x tile [b][k] bf16
    __shared__ float red[8];

    const int tid   = threadIdx.x;
    const int split = blockIdx.x >> 8;
    const int tile  = blockIdx.x & 255;
    const int o0    = tile * OT;
    const int k0    = split * kps;
    const int nch   = kps / KC;
    float* outp = (split == 0) ? out : pbuf + (size_t)(split - 1) * ((size_t)BN * OUTN);

    const int c = tid & 7;     // k-quad index
    const int r = tid >> 3;    // o-row index 0..31

    const size_t wbase = (size_t)(o0 + r) * INN + k0;
    const f4* pi4 = (const f4*)(w_pi   + wbase) + c;
    const f4* r14 = (const f4*)(w_rho1 + wbase) + c;
    const f4* r24 = (const f4*)(w_rho2 + wbase) + c;
    const f4* ep4 = (const f4*)(eps_w  + wbase) + c;
    const f4* gm4 = (const f4*)(gum_w  + 2 * wbase) + 2 * c;

    // x staging: thread covers row xrr, 16-short half xcc
    const int xrr = tid >> 1;           // 0..127
    const int xcc = (tid & 1) * 16;     // 0 or 16
    const short* xsrc = xb + (size_t)xrr * INN + k0 + xcc;

    f32x4 acc00 = {0.f,0.f,0.f,0.f}, acc01 = {0.f,0.f,0.f,0.f};
    f32x4 acc10 = {0.f,0.f,0.f,0.f}, acc11 = {0.f,0.f,0.f,0.f};
    float priorAcc = 0.0f, postAcc = 0.0f;

    // MFMA lane geometry
    const int wv_  = tid >> 6;          // wave 0..3 -> b-slice 32*wv_
    const int lane = tid & 63;
    const int lrow = lane & 15;
    const int lgo  = (lane >> 4) * 8;   // bf16 col offset of this lane's frag

    // prologue prefetch: chunk 0
    f4 vpi = pi4[0], vr1 = r14[0], vr2 = r24[0], vep = ep4[0];
    f4 vga = gm4[0], vgb = gm4[1];
    bf16x8 xv0 = *(const bf16x8*)(xsrc);
    bf16x8 xv1 = *(const bf16x8*)(xsrc + 8);

    #pragma unroll 1
    for (int t = 0; t < nch; ++t) {
        // --- sample 4 weights + accumulate log-probs (LSE, consts folded) ---
        h4 wb;
        #pragma unroll
        for (int i = 0; i < 4; ++i) {
            const f4& g = (i < 2) ? vga : vgb;
            float g0 = g.v[(i & 1) * 2], g1 = g.v[(i & 1) * 2 + 1];
            float pi_ = vpi.v[i], ep = vep.v[i];
            float s1  = __logf(1.0f + __expf(vr1.v[i]));
            float s2  = __logf(1.0f + __expf(vr2.v[i]));
            float ls1 = __logf(s1), ls2 = __logf(s2);
            bool  m1  = ((1.0f - pi_) + g1) > (pi_ + g0);
            float sm  = m1 ? s1 : s2;
            float so  = m1 ? s2 : s1;
            float lsm = m1 ? ls1 : ls2;
            float lso = m1 ? ls2 : ls1;
            float wm  = m1 ? pi_ : 1.0f - pi_;
            float w   = sm * ep;
            wb.v[i] = f2bf(w);
            float wsq = w * w;
            float dlp = 5.9914645f - 79999.5f * wsq;
            priorAcc += -0.5f * wsq + __logf(1.0f + __expf(dlp));   // -C-ln2 folded
            float uo   = __fdividef(w, so);
            float epsq = ep * ep;
            float dlq  = 0.5f * (epsq - uo * uo) + (lsm - lso);
            postAcc += -0.5f * epsq - lsm
                       + __logf(wm + (1.0f - wm) * __expf(dlq));    // -C folded
        }

        __syncthreads();             // previous chunk's frag reads done
        *(h4*)&Wt[r][4 * c] = wb;
        *(bf16x8*)&Xs[xrr][xcc]     = xv0;
        *(bf16x8*)&Xs[xrr][xcc + 8] = xv1;
        __syncthreads();             // tiles ready

        // --- prefetch t+1 (issue here: latency partially hides under MFMA,
        //     consumed at next sample; no barrier in between) ---
        const int tn = (t + 1 < nch) ? t + 1 : 0;
        vpi = pi4[8*tn]; vr1 = r14[8*tn]; vr2 = r24[8*tn]; vep = ep4[8*tn];
        vga = gm4[16*tn]; vgb = gm4[16*tn + 1];
        xv0 = *(const bf16x8*)(xsrc + 32*tn);
        xv1 = *(const bf16x8*)(xsrc + 32*tn + 8);

        // --- MFMA: A = x tile (M=b), B = W tile (N=o), K=32 ---
        bf16x8 a0 = *(const bf16x8*)&Xs[32 * wv_      + lrow][lgo];
        bf16x8 a1 = *(const bf16x8*)&Xs[32 * wv_ + 16 + lrow][lgo];
        bf16x8 b0 = *(const bf16x8*)&Wt[lrow     ][lgo];
        bf16x8 b1 = *(const bf16x8*)&Wt[16 + lrow][lgo];
        acc00 = __builtin_amdgcn_mfma_f32_16x16x32_bf16(a0, b0, acc00, 0, 0, 0);
        acc01 = __builtin_amdgcn_mfma_f32_16x16x32_bf16(a0, b1, acc01, 0, 0, 0);
        acc10 = __builtin_amdgcn_mfma_f32_16x16x32_bf16(a1, b0, acc10, 0, 0, 0);
        acc11 = __builtin_amdgcn_mfma_f32_16x16x32_bf16(a1, b1, acc11, 0, 0, 0);
    }

    // fold per-element constants: prior -(C+ln2), post -C, 4*nch elems/thread
    {
        const float ne = (float)(4 * nch);
        priorAcc -= ne * (C_HLOG2PI + C_LN2);
        postAcc  -= ne * C_HLOG2PI;
    }

    // epilogue: C/D layout col=lane&15 (o), row=(lane>>4)*4+reg (b)
    {
        const int oc = o0 + lrow;
        const int bb = 32 * wv_ + (lane >> 4) * 4;
        const float bv0 = bias ? bias[oc]      : 0.0f;
        const float bv1 = bias ? bias[oc + 16] : 0.0f;
        #pragma unroll
        for (int j = 0; j < 4; ++j) {
            outp[(size_t)(bb      + j) * OUTN + oc     ] = acc00[j] + bv0;
            outp[(size_t)(bb      + j) * OUTN + oc + 16] = acc01[j] + bv1;
            outp[(size_t)(bb + 16 + j) * OUTN + oc     ] = acc10[j] + bv0;
            outp[(size_t)(bb + 16 + j) * OUTN + oc + 16] = acc11[j] + bv1;
        }
    }

    // deterministic block reduction of log-prob partials
    #pragma unroll
    for (int off = 32; off; off >>= 1) {
        priorAcc += __shfl_down(priorAcc, off);
        postAcc  += __shfl_down(postAcc, off);
    }
    if ((tid & 63) == 0) { red[wv_] = priorAcc; red[4 + wv_] = postAcc; }
    __syncthreads();
    if (tid == 0) {
        partials[2*blockIdx.x    ] = red[0] + red[1] + red[2] + red[3];
        partials[2*blockIdx.x + 1] = red[4] + red[5] + red[6] + red[7];
    }
}

__global__ __launch_bounds__(256)
void bayes_bias(const float* __restrict__ b_pi, const float* __restrict__ b_rho1,
                const float* __restrict__ b_rho2, const float* __restrict__ eps_b,
                const float* __restrict__ gum_b,
                float* __restrict__ bias_vals, float* __restrict__ bpart)
{
    __shared__ float red[8];
    const int tid = threadIdx.x;
    const int o = blockIdx.x * 256 + tid;      // 32 blocks x 256 = 8192
    float pi_ = b_pi[o], rho1 = b_rho1[o], rho2 = b_rho2[o], ep = eps_b[o];
    float g0 = gum_b[2*o], g1 = gum_b[2*o + 1];
    float s1, ls1, s2, ls2;
    float w = sample_w(pi_, rho1, rho2, ep, g0, g1, s1, ls1, s2, ls2);
    bias_vals[o] = w;
    float pa = prior_lp(w);
    float qa = post_lp(w, pi_, s1, ls1, s2, ls2);
    #pragma unroll
    for (int off = 32; off; off >>= 1) {
        pa += __shfl_down(pa, off);
        qa += __shfl_down(qa, off);
    }
    const int wave = tid >> 6;
    if ((tid & 63) == 0) { red[wave] = pa; red[4 + wave] = qa; }
    __syncthreads();
    if (tid == 0) {
        bpart[2*blockIdx.x    ] = red[0] + red[1] + red[2] + red[3];
        bpart[2*blockIdx.x + 1] = red[4] + red[5] + red[6] + red[7];
    }
}

__global__ __launch_bounds__(256)
void bayes_reduce(float* __restrict__ out, const float* __restrict__ pbuf,
                  const float* __restrict__ bias, int nsplit)
{
    const size_t i = ((size_t)blockIdx.x * 256 + threadIdx.x) * 4;   // 1024 blocks
    const int o = (int)(i & (OUTN - 1));
    f4 a  = *(const f4*)&out[i];
    f4 bq = *(const f4*)&bias[o];
    #pragma unroll 1
    for (int s = 0; s < nsplit - 1; ++s) {
        f4 p = *(const f4*)&pbuf[(size_t)s * ((size_t)BN * OUTN) + i];
        #pragma unroll
        for (int j = 0; j < 4; ++j) a.v[j] += p.v[j];
    }
    #pragma unroll
    for (int j = 0; j < 4; ++j) a.v[j] += bq.v[j];
    *(f4*)&out[i] = a;
}

__global__ __launch_bounds__(256)
void bayes_final(const float* __restrict__ partials, int cnt,
                 float* __restrict__ out_scalars)
{
    __shared__ double sp[4], sq[4];
    const int tid = threadIdx.x;   // 256
    double p = 0.0, q = 0.0;
    for (int j = tid; j < cnt; j += 256) {
        p += (double)partials[2*j];
        q += (double)partials[2*j + 1];
    }
    #pragma unroll
    for (int off = 32; off; off >>= 1) {
        p += __shfl_down(p, off);
        q += __shfl_down(q, off);
    }
    const int wave = tid >> 6;
    if ((tid & 63) == 0) { sp[wave] = p; sq[wave] = q; }
    __syncthreads();
    if (tid == 0) {
        out_scalars[0] = (float)(sp[0] + sp[1] + sp[2] + sp[3]);
        out_scalars[1] = (float)(sq[0] + sq[1] + sq[2] + sq[3]);
    }
}

} // namespace

extern "C" void kernel_launch(void* const* d_in, const int* in_sizes, int n_in,
                              void* d_out, int out_size, void* d_ws, size_t ws_size,
                              hipStream_t stream) {
    (void)in_sizes; (void)n_in; (void)out_size;
    const float* x      = (const float*)d_in[0];
    const float* w_pi   = (const float*)d_in[1];
    const float* w_rho1 = (const float*)d_in[2];
    const float* w_rho2 = (const float*)d_in[3];
    const float* b_pi   = (const float*)d_in[4];
    const float* b_rho1 = (const float*)d_in[5];
    const float* b_rho2 = (const float*)d_in[6];
    const float* eps_w  = (const float*)d_in[7];
    const float* eps_b  = (const float*)d_in[8];
    const float* gum_w  = (const float*)d_in[9];
    const float* gum_b  = (const float*)d_in[10];

    float* out = (float*)d_out;
    float* ws  = (float*)d_ws;
    // ws layout (floats):
    //   [0, 8192)           bias values
    //   [8192, 12288)       logp partials: main blocks (2*256*NS), then bias blocks
    //   [16384, 278528)     x in bf16 (524288 shorts)
    //   [540672, ...)       (NS-1) partial GEMM outputs, 1048576 floats each
    float* bias_vals = ws;
    float* partials  = ws + 8192;
    short* xb        = (short*)(ws + 16384);
    float* pbuf      = ws + 540672;

    const size_t outElems = (size_t)BN * OUTN;
    int NS = 1;
    if      (ws_size >= (540672 + 7 * outElems) * sizeof(float)) NS = 8;
    else if (ws_size >= (540672 + 3 * outElems) * sizeof(float)) NS = 4;
    else if (ws_size >= (540672 + 1 * outElems) * sizeof(float)) NS = 2;

    float* bpart = partials + 2 * 256 * NS;
    const int cnt = 256 * NS + 32;

    xcast<<<(BN * INN) / (256 * 8), 256, 0, stream>>>(x, xb);
    bayes_bias<<<32, 256, 0, stream>>>(b_pi, b_rho1, b_rho2, eps_b, gum_b,
                                       bias_vals, bpart);

    if (NS == 1) {
        bayes_main<<<256, NT, 0, stream>>>(xb, w_pi, w_rho1, w_rho2, eps_w, gum_w,
                                           bias_vals, out, pbuf, partials, INN);
    } else {
        bayes_main<<<256 * NS, NT, 0, stream>>>(xb, w_pi, w_rho1, w_rho2, eps_w, gum_w,
                                                nullptr, out, pbuf, partials, INN / NS);
        bayes_reduce<<<(int)(outElems / 4 / 256), 256, 0, stream>>>(out, pbuf,
                                                                    bias_vals, NS);
    }
    bayes_final<<<1, 256, 0, stream>>>(partials, cnt, out + outElems);
}

// Round 7
// 205.003 us; speedup vs baseline: 1.8145x; 1.8145x over previous
//
#include <hip/hip_runtime.h>

#define OUTN 8192
#define INN  4096
#define BN   128

namespace {

typedef __attribute__((ext_vector_type(8))) short bf16x8;   // 8 bf16 (4 VGPRs)
typedef __attribute__((ext_vector_type(4))) float f32x4;

struct alignas(16) f4 { float v[4]; };
struct alignas(8)  h4 { short v[4]; };

constexpr float C_HLOG2PI = 0.91893853f;   // 0.5*log(2*pi)
constexpr float C_LN2     = 0.69314718f;

__device__ __forceinline__ short f2bf(float f) {
    unsigned u = __float_as_uint(f);
    u += 0x7fffu + ((u >> 16) & 1u);       // round-to-nearest-even
    return (short)(u >> 16);
}

// ---- full-form helpers (tiny bias kernel only) ----
__device__ __forceinline__ float prior_lp(float w) {
    float lp1 = -0.5f * w * w - C_HLOG2PI;
    float a   = w * 400.0f;
    float lp2 = -0.5f * a * a + 5.0725261f;
    return __logf(0.5f * __expf(lp1) + 0.5f * __expf(lp2));
}
__device__ __forceinline__ float post_lp(float w, float pi_, float s1, float ls1,
                                         float s2, float ls2) {
    float u1  = __fdividef(w, s1);
    float u2  = __fdividef(w, s2);
    float lq1 = -0.5f * u1 * u1 - ls1 - C_HLOG2PI;
    float lq2 = -0.5f * u2 * u2 - ls2 - C_HLOG2PI;
    return __logf(pi_ * __expf(lq1) + (1.0f - pi_) * __expf(lq2));
}
__device__ __forceinline__ float sample_w(float pi_, float rho1, float rho2, float ep,
                                          float g0, float g1,
                                          float& s1, float& ls1, float& s2, float& ls2) {
    s1  = __logf(1.0f + __expf(rho1));
    s2  = __logf(1.0f + __expf(rho2));
    ls1 = __logf(s1);
    ls2 = __logf(s2);
    bool mode1 = ((1.0f - pi_) + g1) > (pi_ + g0);
    return (mode1 ? s1 : s2) * ep;
}

constexpr int OT = 32;    // output rows per tile
constexpr int KC = 32;    // K-chunk (== MFMA K)
constexpr int NT = 256;
constexpr int KSTR = 40;  // bf16 LDS row stride (80 B: 16B-aligned, bank-spread)

__global__ __launch_bounds__(256)
void xcast(const float* __restrict__ x, short* __restrict__ xb)
{
    const int i = (blockIdx.x * 256 + threadIdx.x) * 8;   // 256 blocks
    f4 a = *(const f4*)&x[i];
    f4 b = *(const f4*)&x[i + 4];
    h4 o0, o1;
    #pragma unroll
    for (int j = 0; j < 4; ++j) { o0.v[j] = f2bf(a.v[j]); o1.v[j] = f2bf(b.v[j]); }
    *(h4*)&xb[i]     = o0;
    *(h4*)&xb[i + 4] = o1;
}

// launch_bounds(256,6): unified VGPR cap ~85 — fits the working set
// (16 acc + 24 stream-prefetch + 8 x + ~25 addr/temps) with NO scratch
// spill, while still allowing 6 blocks/CU (24 waves/CU = 75%).
// (256,8) capped at 64 unified -> 32 arch VGPRs -> spills (R6, +335MB fetch).
__global__ __launch_bounds__(NT, 6)
void bayes_main(const short* __restrict__ xb,      // x in bf16, [BN][INN]
                const float* __restrict__ w_pi,
                const float* __restrict__ w_rho1,
                const float* __restrict__ w_rho2,
                const float* __restrict__ eps_w,
                const float* __restrict__ gum_w,
                const float* __restrict__ bias,    // non-null only when nsplit==1
                float* __restrict__ out,
                float* __restrict__ pbuf,
                float* __restrict__ partials,
                int kps)
{
    __shared__ alignas(16) short Wt[OT][KSTR];   // W tile [o][k] bf16
    __shared__ alignas(16) short Xs[BN][KSTR];   // x tile [b][k] bf16
    __shared__ float red[8];

    const int tid   = threadIdx.x;
    const int split = blockIdx.x >> 8;
    const int tile  = blockIdx.x & 255;
    const int o0    = tile * OT;
    const int k0    = split * kps;
    const int nch   = kps / KC;
    float* outp = (split == 0) ? out : pbuf + (size_t)(split - 1) * ((size_t)BN * OUTN);

    const int c = tid & 7;     // k-quad index
    const int r = tid >> 3;    // o-row index 0..31

    const size_t wbase = (size_t)(o0 + r) * INN + k0;
    const f4* pi4 = (const f4*)(w_pi   + wbase) + c;
    const f4* r14 = (const f4*)(w_rho1 + wbase) + c;
    const f4* r24 = (const f4*)(w_rho2 + wbase) + c;
    const f4* ep4 = (const f4*)(eps_w  + wbase) + c;
    const f4* gm4 = (const f4*)(gum_w  + 2 * wbase) + 2 * c;

    // x staging: thread covers row xrr, 16-short half xcc
    const int xrr = tid >> 1;           // 0..127
    const int xcc = (tid & 1) * 16;     // 0 or 16
    const short* xsrc = xb + (size_t)xrr * INN + k0 + xcc;

    f32x4 acc00 = {0.f,0.f,0.f,0.f}, acc01 = {0.f,0.f,0.f,0.f};
    f32x4 acc10 = {0.f,0.f,0.f,0.f}, acc11 = {0.f,0.f,0.f,0.f};
    float priorAcc = 0.0f, postAcc = 0.0f;

    // MFMA lane geometry
    const int wv_  = tid >> 6;          // wave 0..3 -> b-slice 32*wv_
    const int lane = tid & 63;
    const int lrow = lane & 15;
    const int lgo  = (lane >> 4) * 8;   // bf16 col offset of this lane's frag

    // prologue prefetch: chunk 0
    f4 vpi = pi4[0], vr1 = r14[0], vr2 = r24[0], vep = ep4[0];
    f4 vga = gm4[0], vgb = gm4[1];
    bf16x8 xv0 = *(const bf16x8*)(xsrc);
    bf16x8 xv1 = *(const bf16x8*)(xsrc + 8);

    #pragma unroll 1
    for (int t = 0; t < nch; ++t) {
        // --- sample 4 weights + accumulate log-probs (LSE, consts folded) ---
        h4 wb;
        #pragma unroll
        for (int i = 0; i < 4; ++i) {
            const f4& g = (i < 2) ? vga : vgb;
            float g0 = g.v[(i & 1) * 2], g1 = g.v[(i & 1) * 2 + 1];
            float pi_ = vpi.v[i], ep = vep.v[i];
            float s1  = __logf(1.0f + __expf(vr1.v[i]));
            float s2  = __logf(1.0f + __expf(vr2.v[i]));
            float ls1 = __logf(s1), ls2 = __logf(s2);
            bool  m1  = ((1.0f - pi_) + g1) > (pi_ + g0);
            float sm  = m1 ? s1 : s2;
            float so  = m1 ? s2 : s1;
            float lsm = m1 ? ls1 : ls2;
            float lso = m1 ? ls2 : ls1;
            float wm  = m1 ? pi_ : 1.0f - pi_;
            float w   = sm * ep;
            wb.v[i] = f2bf(w);
            float wsq = w * w;
            float dlp = 5.9914645f - 79999.5f * wsq;
            priorAcc += -0.5f * wsq + __logf(1.0f + __expf(dlp));   // -C-ln2 folded
            float uo   = __fdividef(w, so);
            float epsq = ep * ep;
            float dlq  = 0.5f * (epsq - uo * uo) + (lsm - lso);
            postAcc += -0.5f * epsq - lsm
                       + __logf(wm + (1.0f - wm) * __expf(dlq));    // -C folded
        }

        __syncthreads();             // previous chunk's frag reads done
        *(h4*)&Wt[r][4 * c] = wb;
        *(bf16x8*)&Xs[xrr][xcc]     = xv0;
        *(bf16x8*)&Xs[xrr][xcc + 8] = xv1;
        __syncthreads();             // tiles ready

        // --- prefetch t+1 (after the barrier: no vmcnt(0)-drain at s_barrier;
        //     latency covered by MFMA phase + other resident blocks) ---
        const int tn = (t + 1 < nch) ? t + 1 : 0;
        vpi = pi4[8*tn]; vr1 = r14[8*tn]; vr2 = r24[8*tn]; vep = ep4[8*tn];
        vga = gm4[16*tn]; vgb = gm4[16*tn + 1];
        xv0 = *(const bf16x8*)(xsrc + 32*tn);
        xv1 = *(const bf16x8*)(xsrc + 32*tn + 8);

        // --- MFMA: A = x tile (M=b), B = W tile (N=o), K=32 ---
        bf16x8 a0 = *(const bf16x8*)&Xs[32 * wv_      + lrow][lgo];
        bf16x8 a1 = *(const bf16x8*)&Xs[32 * wv_ + 16 + lrow][lgo];
        bf16x8 b0 = *(const bf16x8*)&Wt[lrow     ][lgo];
        bf16x8 b1 = *(const bf16x8*)&Wt[16 + lrow][lgo];
        acc00 = __builtin_amdgcn_mfma_f32_16x16x32_bf16(a0, b0, acc00, 0, 0, 0);
        acc01 = __builtin_amdgcn_mfma_f32_16x16x32_bf16(a0, b1, acc01, 0, 0, 0);
        acc10 = __builtin_amdgcn_mfma_f32_16x16x32_bf16(a1, b0, acc10, 0, 0, 0);
        acc11 = __builtin_amdgcn_mfma_f32_16x16x32_bf16(a1, b1, acc11, 0, 0, 0);
    }

    // fold per-element constants: prior -(C+ln2), post -C, 4*nch elems/thread
    {
        const float ne = (float)(4 * nch);
        priorAcc -= ne * (C_HLOG2PI + C_LN2);
        postAcc  -= ne * C_HLOG2PI;
    }

    // epilogue: C/D layout col=lane&15 (o), row=(lane>>4)*4+reg (b)
    {
        const int oc = o0 + lrow;
        const int bb = 32 * wv_ + (lane >> 4) * 4;
        const float bv0 = bias ? bias[oc]      : 0.0f;
        const float bv1 = bias ? bias[oc + 16] : 0.0f;
        #pragma unroll
        for (int j = 0; j < 4; ++j) {
            outp[(size_t)(bb      + j) * OUTN + oc     ] = acc00[j] + bv0;
            outp[(size_t)(bb      + j) * OUTN + oc + 16] = acc01[j] + bv1;
            outp[(size_t)(bb + 16 + j) * OUTN + oc     ] = acc10[j] + bv0;
            outp[(size_t)(bb + 16 + j) * OUTN + oc + 16] = acc11[j] + bv1;
        }
    }

    // deterministic block reduction of log-prob partials
    #pragma unroll
    for (int off = 32; off; off >>= 1) {
        priorAcc += __shfl_down(priorAcc, off);
        postAcc  += __shfl_down(postAcc, off);
    }
    if ((tid & 63) == 0) { red[wv_] = priorAcc; red[4 + wv_] = postAcc; }
    __syncthreads();
    if (tid == 0) {
        partials[2*blockIdx.x    ] = red[0] + red[1] + red[2] + red[3];
        partials[2*blockIdx.x + 1] = red[4] + red[5] + red[6] + red[7];
    }
}

__global__ __launch_bounds__(256)
void bayes_bias(const float* __restrict__ b_pi, const float* __restrict__ b_rho1,
                const float* __restrict__ b_rho2, const float* __restrict__ eps_b,
                const float* __restrict__ gum_b,
                float* __restrict__ bias_vals, float* __restrict__ bpart)
{
    __shared__ float red[8];
    const int tid = threadIdx.x;
    const int o = blockIdx.x * 256 + tid;      // 32 blocks x 256 = 8192
    float pi_ = b_pi[o], rho1 = b_rho1[o], rho2 = b_rho2[o], ep = eps_b[o];
    float g0 = gum_b[2*o], g1 = gum_b[2*o + 1];
    float s1, ls1, s2, ls2;
    float w = sample_w(pi_, rho1, rho2, ep, g0, g1, s1, ls1, s2, ls2);
    bias_vals[o] = w;
    float pa = prior_lp(w);
    float qa = post_lp(w, pi_, s1, ls1, s2, ls2);
    #pragma unroll
    for (int off = 32; off; off >>= 1) {
        pa += __shfl_down(pa, off);
        qa += __shfl_down(qa, off);
    }
    const int wave = tid >> 6;
    if ((tid & 63) == 0) { red[wave] = pa; red[4 + wave] = qa; }
    __syncthreads();
    if (tid == 0) {
        bpart[2*blockIdx.x    ] = red[0] + red[1] + red[2] + red[3];
        bpart[2*blockIdx.x + 1] = red[4] + red[5] + red[6] + red[7];
    }
}

__global__ __launch_bounds__(256)
void bayes_reduce(float* __restrict__ out, const float* __restrict__ pbuf,
                  const float* __restrict__ bias, int nsplit)
{
    const size_t i = ((size_t)blockIdx.x * 256 + threadIdx.x) * 4;   // 1024 blocks
    const int o = (int)(i & (OUTN - 1));
    f4 a  = *(const f4*)&out[i];
    f4 bq = *(const f4*)&bias[o];
    #pragma unroll 1
    for (int s = 0; s < nsplit - 1; ++s) {
        f4 p = *(const f4*)&pbuf[(size_t)s * ((size_t)BN * OUTN) + i];
        #pragma unroll
        for (int j = 0; j < 4; ++j) a.v[j] += p.v[j];
    }
    #pragma unroll
    for (int j = 0; j < 4; ++j) a.v[j] += bq.v[j];
    *(f4*)&out[i] = a;
}

__global__ __launch_bounds__(256)
void bayes_final(const float* __restrict__ partials, int cnt,
                 float* __restrict__ out_scalars)
{
    __shared__ double sp[4], sq[4];
    const int tid = threadIdx.x;   // 256
    double p = 0.0, q = 0.0;
    for (int j = tid; j < cnt; j += 256) {
        p += (double)partials[2*j];
        q += (double)partials[2*j + 1];
    }
    #pragma unroll
    for (int off = 32; off; off >>= 1) {
        p += __shfl_down(p, off);
        q += __shfl_down(q, off);
    }
    const int wave = tid >> 6;
    if ((tid & 63) == 0) { sp[wave] = p; sq[wave] = q; }
    __syncthreads();
    if (tid == 0) {
        out_scalars[0] = (float)(sp[0] + sp[1] + sp[2] + sp[3]);
        out_scalars[1] = (float)(sq[0] + sq[1] + sq[2] + sq[3]);
    }
}

} // namespace

extern "C" void kernel_launch(void* const* d_in, const int* in_sizes, int n_in,
                              void* d_out, int out_size, void* d_ws, size_t ws_size,
                              hipStream_t stream) {
    (void)in_sizes; (void)n_in; (void)out_size;
    const float* x      = (const float*)d_in[0];
    const float* w_pi   = (const float*)d_in[1];
    const float* w_rho1 = (const float*)d_in[2];
    const float* w_rho2 = (const float*)d_in[3];
    const float* b_pi   = (const float*)d_in[4];
    const float* b_rho1 = (const float*)d_in[5];
    const float* b_rho2 = (const float*)d_in[6];
    const float* eps_w  = (const float*)d_in[7];
    const float* eps_b  = (const float*)d_in[8];
    const float* gum_w  = (const float*)d_in[9];
    const float* gum_b  = (const float*)d_in[10];

    float* out = (float*)d_out;
    float* ws  = (float*)d_ws;
    // ws layout (floats):
    //   [0, 8192)           bias values
    //   [8192, 16384)       logp partials: main blocks (2*256*NS), then bias blocks
    //   [16384, 540672)     x in bf16 (524288 shorts)
    //   [540672, ...)       (NS-1) partial GEMM outputs, 1048576 floats each
    float* bias_vals = ws;
    float* partials  = ws + 8192;
    short* xb        = (short*)(ws + 16384);
    float* pbuf      = ws + 540672;

    const size_t outElems = (size_t)BN * OUTN;
    int NS = 1;
    if      (ws_size >= (540672 + 7 * outElems) * sizeof(float)) NS = 8;
    else if (ws_size >= (540672 + 3 * outElems) * sizeof(float)) NS = 4;
    else if (ws_size >= (540672 + 1 * outElems) * sizeof(float)) NS = 2;

    float* bpart = partials + 2 * 256 * NS;
    const int cnt = 256 * NS + 32;

    xcast<<<(BN * INN) / (256 * 8), 256, 0, stream>>>(x, xb);
    bayes_bias<<<32, 256, 0, stream>>>(b_pi, b_rho1, b_rho2, eps_b, gum_b,
                                       bias_vals, bpart);

    if (NS == 1) {
        bayes_main<<<256, NT, 0, stream>>>(xb, w_pi, w_rho1, w_rho2, eps_w, gum_w,
                                           bias_vals, out, pbuf, partials, INN);
    } else {
        bayes_main<<<256 * NS, NT, 0, stream>>>(xb, w_pi, w_rho1, w_rho2, eps_w, gum_w,
                                                nullptr, out, pbuf, partials, INN / NS);
        bayes_reduce<<<(int)(outElems / 4 / 256), 256, 0, stream>>>(out, pbuf,
                                                                    bias_vals, NS);
    }
    bayes_final<<<1, 256, 0, stream>>>(partials, cnt, out + outElems);
}

// Round 8
// 201.522 us; speedup vs baseline: 1.8459x; 1.0173x over previous
//
#include <hip/hip_runtime.h>

#define OUTN 8192
#define INN  4096
#define BN   128

namespace {

typedef __attribute__((ext_vector_type(8))) short bf16x8;   // 8 bf16 (4 VGPRs)
typedef __attribute__((ext_vector_type(4))) float f32x4;

struct alignas(16) f4 { float v[4]; };
struct alignas(8)  h4 { short v[4]; };

constexpr float C_HLOG2PI = 0.91893853f;   // 0.5*log(2*pi)
constexpr float C_LN2     = 0.69314718f;

__device__ __forceinline__ short f2bf(float f) {
    unsigned u = __float_as_uint(f);
    u += 0x7fffu + ((u >> 16) & 1u);       // round-to-nearest-even
    return (short)(u >> 16);
}

// ---- full-form helpers (tiny bias kernel only) ----
__device__ __forceinline__ float prior_lp(float w) {
    float lp1 = -0.5f * w * w - C_HLOG2PI;
    float a   = w * 400.0f;
    float lp2 = -0.5f * a * a + 5.0725261f;
    return __logf(0.5f * __expf(lp1) + 0.5f * __expf(lp2));
}
__device__ __forceinline__ float post_lp(float w, float pi_, float s1, float ls1,
                                         float s2, float ls2) {
    float u1  = __fdividef(w, s1);
    float u2  = __fdividef(w, s2);
    float lq1 = -0.5f * u1 * u1 - ls1 - C_HLOG2PI;
    float lq2 = -0.5f * u2 * u2 - ls2 - C_HLOG2PI;
    return __logf(pi_ * __expf(lq1) + (1.0f - pi_) * __expf(lq2));
}
__device__ __forceinline__ float sample_w(float pi_, float rho1, float rho2, float ep,
                                          float g0, float g1,
                                          float& s1, float& ls1, float& s2, float& ls2) {
    s1  = __logf(1.0f + __expf(rho1));
    s2  = __logf(1.0f + __expf(rho2));
    ls1 = __logf(s1);
    ls2 = __logf(s2);
    bool mode1 = ((1.0f - pi_) + g1) > (pi_ + g0);
    return (mode1 ? s1 : s2) * ep;
}

constexpr int OT = 32;    // output rows per tile
constexpr int KC = 32;    // K-chunk (== MFMA K)
constexpr int NT = 256;
constexpr int KSTR = 40;  // bf16 LDS row stride (80 B: 16B-aligned, bank-spread)

__global__ __launch_bounds__(256)
void xcast(const float* __restrict__ x, short* __restrict__ xb)
{
    const int i = (blockIdx.x * 256 + threadIdx.x) * 8;   // 256 blocks
    f4 a = *(const f4*)&x[i];
    f4 b = *(const f4*)&x[i + 4];
    h4 o0, o1;
    #pragma unroll
    for (int j = 0; j < 4; ++j) { o0.v[j] = f2bf(a.v[j]); o1.v[j] = f2bf(b.v[j]); }
    *(h4*)&xb[i]     = o0;
    *(h4*)&xb[i + 4] = o1;
}

// launch_bounds(256,6): unified VGPR cap ~85, no spill (R7: VGPR 40, FETCH
// back to compulsory). Grid is sized 6 blocks/CU to MATCH the cap: R7 ran
// 8/CU against cap 6 -> phases of 6-resident then 2-resident (measured
// occupancy 55% ~= time-average). NS=6 with non-uniform K-splits keeps one
// full-residency phase.
__global__ __launch_bounds__(NT, 6)
void bayes_main(const short* __restrict__ xb,      // x in bf16, [BN][INN]
                const float* __restrict__ w_pi,
                const float* __restrict__ w_rho1,
                const float* __restrict__ w_rho2,
                const float* __restrict__ eps_w,
                const float* __restrict__ gum_w,
                const float* __restrict__ bias,    // non-null only when NS==1
                float* __restrict__ out,
                float* __restrict__ pbuf,
                float* __restrict__ partials,
                int NS)
{
    __shared__ alignas(16) short Wt[OT][KSTR];   // W tile [o][k] bf16
    __shared__ alignas(16) short Xs[BN][KSTR];   // x tile [b][k] bf16
    __shared__ float red[8];

    const int tid   = threadIdx.x;
    const int split = blockIdx.x >> 8;
    const int tile  = blockIdx.x & 255;
    const int o0    = tile * OT;

    // non-uniform K-split: 128 chunks over NS splits
    const int baseCh = 128 / NS;
    const int remCh  = 128 % NS;
    const int nch    = baseCh + (split < remCh ? 1 : 0);
    const int ch0    = split * baseCh + (split < remCh ? split : remCh);
    const int k0     = ch0 * KC;

    float* outp = (split == 0) ? out : pbuf + (size_t)(split - 1) * ((size_t)BN * OUTN);

    const int c = tid & 7;     // k-quad index
    const int r = tid >> 3;    // o-row index 0..31

    const size_t wbase = (size_t)(o0 + r) * INN + k0;
    const f4* pi4 = (const f4*)(w_pi   + wbase) + c;
    const f4* r14 = (const f4*)(w_rho1 + wbase) + c;
    const f4* r24 = (const f4*)(w_rho2 + wbase) + c;
    const f4* ep4 = (const f4*)(eps_w  + wbase) + c;
    const f4* gm4 = (const f4*)(gum_w  + 2 * wbase) + 2 * c;

    // x staging: thread covers row xrr, 16-short half xcc
    const int xrr = tid >> 1;           // 0..127
    const int xcc = (tid & 1) * 16;     // 0 or 16
    const short* xsrc = xb + (size_t)xrr * INN + k0 + xcc;

    f32x4 acc00 = {0.f,0.f,0.f,0.f}, acc01 = {0.f,0.f,0.f,0.f};
    f32x4 acc10 = {0.f,0.f,0.f,0.f}, acc11 = {0.f,0.f,0.f,0.f};
    float priorAcc = 0.0f, postAcc = 0.0f;

    // MFMA lane geometry
    const int wv_  = tid >> 6;          // wave 0..3 -> b-slice 32*wv_
    const int lane = tid & 63;
    const int lrow = lane & 15;
    const int lgo  = (lane >> 4) * 8;   // bf16 col offset of this lane's frag

    // prologue prefetch: chunk 0
    f4 vpi = pi4[0], vr1 = r14[0], vr2 = r24[0], vep = ep4[0];
    f4 vga = gm4[0], vgb = gm4[1];
    bf16x8 xv0 = *(const bf16x8*)(xsrc);
    bf16x8 xv1 = *(const bf16x8*)(xsrc + 8);

    #pragma unroll 1
    for (int t = 0; t < nch; ++t) {
        // --- sample 4 weights + accumulate log-probs (LSE, consts folded) ---
        h4 wb;
        #pragma unroll
        for (int i = 0; i < 4; ++i) {
            const f4& g = (i < 2) ? vga : vgb;
            float g0 = g.v[(i & 1) * 2], g1 = g.v[(i & 1) * 2 + 1];
            float pi_ = vpi.v[i], ep = vep.v[i];
            float s1  = __logf(1.0f + __expf(vr1.v[i]));
            float s2  = __logf(1.0f + __expf(vr2.v[i]));
            float ls1 = __logf(s1), ls2 = __logf(s2);
            bool  m1  = ((1.0f - pi_) + g1) > (pi_ + g0);
            float sm  = m1 ? s1 : s2;
            float so  = m1 ? s2 : s1;
            float lsm = m1 ? ls1 : ls2;
            float lso = m1 ? ls2 : ls1;
            float wm  = m1 ? pi_ : 1.0f - pi_;
            float w   = sm * ep;
            wb.v[i] = f2bf(w);
            float wsq = w * w;
            float dlp = 5.9914645f - 79999.5f * wsq;
            priorAcc += -0.5f * wsq + __logf(1.0f + __expf(dlp));   // -C-ln2 folded
            float uo   = __fdividef(w, so);
            float epsq = ep * ep;
            float dlq  = 0.5f * (epsq - uo * uo) + (lsm - lso);
            postAcc += -0.5f * epsq - lsm
                       + __logf(wm + (1.0f - wm) * __expf(dlq));    // -C folded
        }

        __syncthreads();             // previous chunk's frag reads done
        *(h4*)&Wt[r][4 * c] = wb;
        *(bf16x8*)&Xs[xrr][xcc]     = xv0;
        *(bf16x8*)&Xs[xrr][xcc + 8] = xv1;
        __syncthreads();             // tiles ready

        // --- prefetch t+1 (after the barrier: no vmcnt(0)-drain at s_barrier;
        //     latency covered by MFMA phase + 5 other resident blocks) ---
        const int tn = (t + 1 < nch) ? t + 1 : 0;
        vpi = pi4[8*tn]; vr1 = r14[8*tn]; vr2 = r24[8*tn]; vep = ep4[8*tn];
        vga = gm4[16*tn]; vgb = gm4[16*tn + 1];
        xv0 = *(const bf16x8*)(xsrc + 32*tn);
        xv1 = *(const bf16x8*)(xsrc + 32*tn + 8);

        // --- MFMA: A = x tile (M=b), B = W tile (N=o), K=32 ---
        bf16x8 a0 = *(const bf16x8*)&Xs[32 * wv_      + lrow][lgo];
        bf16x8 a1 = *(const bf16x8*)&Xs[32 * wv_ + 16 + lrow][lgo];
        bf16x8 b0 = *(const bf16x8*)&Wt[lrow     ][lgo];
        bf16x8 b1 = *(const bf16x8*)&Wt[16 + lrow][lgo];
        acc00 = __builtin_amdgcn_mfma_f32_16x16x32_bf16(a0, b0, acc00, 0, 0, 0);
        acc01 = __builtin_amdgcn_mfma_f32_16x16x32_bf16(a0, b1, acc01, 0, 0, 0);
        acc10 = __builtin_amdgcn_mfma_f32_16x16x32_bf16(a1, b0, acc10, 0, 0, 0);
        acc11 = __builtin_amdgcn_mfma_f32_16x16x32_bf16(a1, b1, acc11, 0, 0, 0);
    }

    // fold per-element constants: prior -(C+ln2), post -C, 4*nch elems/thread
    {
        const float ne = (float)(4 * nch);
        priorAcc -= ne * (C_HLOG2PI + C_LN2);
        postAcc  -= ne * C_HLOG2PI;
    }

    // epilogue: C/D layout col=lane&15 (o), row=(lane>>4)*4+reg (b)
    {
        const int oc = o0 + lrow;
        const int bb = 32 * wv_ + (lane >> 4) * 4;
        const float bv0 = bias ? bias[oc]      : 0.0f;
        const float bv1 = bias ? bias[oc + 16] : 0.0f;
        #pragma unroll
        for (int j = 0; j < 4; ++j) {
            outp[(size_t)(bb      + j) * OUTN + oc     ] = acc00[j] + bv0;
            outp[(size_t)(bb      + j) * OUTN + oc + 16] = acc01[j] + bv1;
            outp[(size_t)(bb + 16 + j) * OUTN + oc     ] = acc10[j] + bv0;
            outp[(size_t)(bb + 16 + j) * OUTN + oc + 16] = acc11[j] + bv1;
        }
    }

    // deterministic block reduction of log-prob partials
    #pragma unroll
    for (int off = 32; off; off >>= 1) {
        priorAcc += __shfl_down(priorAcc, off);
        postAcc  += __shfl_down(postAcc, off);
    }
    if ((tid & 63) == 0) { red[wv_] = priorAcc; red[4 + wv_] = postAcc; }
    __syncthreads();
    if (tid == 0) {
        partials[2*blockIdx.x    ] = red[0] + red[1] + red[2] + red[3];
        partials[2*blockIdx.x + 1] = red[4] + red[5] + red[6] + red[7];
    }
}

__global__ __launch_bounds__(256)
void bayes_bias(const float* __restrict__ b_pi, const float* __restrict__ b_rho1,
                const float* __restrict__ b_rho2, const float* __restrict__ eps_b,
                const float* __restrict__ gum_b,
                float* __restrict__ bias_vals, float* __restrict__ bpart)
{
    __shared__ float red[8];
    const int tid = threadIdx.x;
    const int o = blockIdx.x * 256 + tid;      // 32 blocks x 256 = 8192
    float pi_ = b_pi[o], rho1 = b_rho1[o], rho2 = b_rho2[o], ep = eps_b[o];
    float g0 = gum_b[2*o], g1 = gum_b[2*o + 1];
    float s1, ls1, s2, ls2;
    float w = sample_w(pi_, rho1, rho2, ep, g0, g1, s1, ls1, s2, ls2);
    bias_vals[o] = w;
    float pa = prior_lp(w);
    float qa = post_lp(w, pi_, s1, ls1, s2, ls2);
    #pragma unroll
    for (int off = 32; off; off >>= 1) {
        pa += __shfl_down(pa, off);
        qa += __shfl_down(qa, off);
    }
    const int wave = tid >> 6;
    if ((tid & 63) == 0) { red[wave] = pa; red[4 + wave] = qa; }
    __syncthreads();
    if (tid == 0) {
        bpart[2*blockIdx.x    ] = red[0] + red[1] + red[2] + red[3];
        bpart[2*blockIdx.x + 1] = red[4] + red[5] + red[6] + red[7];
    }
}

__global__ __launch_bounds__(256)
void bayes_reduce(float* __restrict__ out, const float* __restrict__ pbuf,
                  const float* __restrict__ bias, int nsplit)
{
    const size_t i = ((size_t)blockIdx.x * 256 + threadIdx.x) * 4;   // 1024 blocks
    const int o = (int)(i & (OUTN - 1));
    f4 a  = *(const f4*)&out[i];
    f4 bq = *(const f4*)&bias[o];
    #pragma unroll 1
    for (int s = 0; s < nsplit - 1; ++s) {
        f4 p = *(const f4*)&pbuf[(size_t)s * ((size_t)BN * OUTN) + i];
        #pragma unroll
        for (int j = 0; j < 4; ++j) a.v[j] += p.v[j];
    }
    #pragma unroll
    for (int j = 0; j < 4; ++j) a.v[j] += bq.v[j];
    *(f4*)&out[i] = a;
}

__global__ __launch_bounds__(256)
void bayes_final(const float* __restrict__ partials, int cnt,
                 float* __restrict__ out_scalars)
{
    __shared__ double sp[4], sq[4];
    const int tid = threadIdx.x;   // 256
    double p = 0.0, q = 0.0;
    for (int j = tid; j < cnt; j += 256) {
        p += (double)partials[2*j];
        q += (double)partials[2*j + 1];
    }
    #pragma unroll
    for (int off = 32; off; off >>= 1) {
        p += __shfl_down(p, off);
        q += __shfl_down(q, off);
    }
    const int wave = tid >> 6;
    if ((tid & 63) == 0) { sp[wave] = p; sq[wave] = q; }
    __syncthreads();
    if (tid == 0) {
        out_scalars[0] = (float)(sp[0] + sp[1] + sp[2] + sp[3]);
        out_scalars[1] = (float)(sq[0] + sq[1] + sq[2] + sq[3]);
    }
}

} // namespace

extern "C" void kernel_launch(void* const* d_in, const int* in_sizes, int n_in,
                              void* d_out, int out_size, void* d_ws, size_t ws_size,
                              hipStream_t stream) {
    (void)in_sizes; (void)n_in; (void)out_size;
    const float* x      = (const float*)d_in[0];
    const float* w_pi   = (const float*)d_in[1];
    const float* w_rho1 = (const float*)d_in[2];
    const float* w_rho2 = (const float*)d_in[3];
    const float* b_pi   = (const float*)d_in[4];
    const float* b_rho1 = (const float*)d_in[5];
    const float* b_rho2 = (const float*)d_in[6];
    const float* eps_w  = (const float*)d_in[7];
    const float* eps_b  = (const float*)d_in[8];
    const float* gum_w  = (const float*)d_in[9];
    const float* gum_b  = (const float*)d_in[10];

    float* out = (float*)d_out;
    float* ws  = (float*)d_ws;
    // ws layout (floats):
    //   [0, 8192)           bias values
    //   [8192, 16384)       logp partials: main blocks (2*256*NS), then bias blocks
    //   [16384, 540672)     x in bf16 (524288 shorts)
    //   [540672, ...)       (NS-1) partial GEMM outputs, 1048576 floats each
    float* bias_vals = ws;
    float* partials  = ws + 8192;
    short* xb        = (short*)(ws + 16384);
    float* pbuf      = ws + 540672;

    const size_t outElems = (size_t)BN * OUTN;
    int NS = 1;
    if      (ws_size >= (540672 + 5 * outElems) * sizeof(float)) NS = 6;
    else if (ws_size >= (540672 + 3 * outElems) * sizeof(float)) NS = 4;
    else if (ws_size >= (540672 + 1 * outElems) * sizeof(float)) NS = 2;

    float* bpart = partials + 2 * 256 * NS;
    const int cnt = 256 * NS + 32;

    xcast<<<(BN * INN) / (256 * 8), 256, 0, stream>>>(x, xb);
    bayes_bias<<<32, 256, 0, stream>>>(b_pi, b_rho1, b_rho2, eps_b, gum_b,
                                       bias_vals, bpart);

    if (NS == 1) {
        bayes_main<<<256, NT, 0, stream>>>(xb, w_pi, w_rho1, w_rho2, eps_w, gum_w,
                                           bias_vals, out, pbuf, partials, 1);
    } else {
        bayes_main<<<256 * NS, NT, 0, stream>>>(xb, w_pi, w_rho1, w_rho2, eps_w, gum_w,
                                                nullptr, out, pbuf, partials, NS);
        bayes_reduce<<<(int)(outElems / 4 / 256), 256, 0, stream>>>(out, pbuf,
                                                                    bias_vals, NS);
    }
    bayes_final<<<1, 256, 0, stream>>>(partials, cnt, out + outElems);
}